// Round 1
// baseline (39779.041 us; speedup 1.0000x reference)
//
#include <hip/hip_runtime.h>
#include <math.h>

// ---------------------------------------------------------------------------
// 2-layer tanh RNN scan, B=128, T=1024, H=768.
// Persistent cooperative-style kernel (regular launch; grid=256 WGs of 256
// threads = 1 WG/CU on MI355X's 256 CUs -> all workgroups resident).
//
// Numerics: weights & h state kept as bf16 (hi,lo) pairs; each matmul uses
// 3 MFMA products (hi*hi + hi*lo + lo*hi) with fp32 accumulation -> ~fp32
// precision (residual ~1e-6/step).
//
// Work split:
//   WG 0..63    (L1): rows rg*32..+31, cols cg*48..+47 of layer-1 (W_hh1)
//   WG 64..255  (L2): rows rg*32..+31, cols cg*16..+15 of layer-2 (W_ih2,W_hh2)
// Weight MFMA B-fragments live in VGPRs for the whole kernel (loaded once).
// Per step:
//   phase1: L1 computes h1(t) (3-product MFMA over K=768, K split over 4
//           waves, LDS reduce, + x-term + biases, tanh, store hi/lo);
//           L2 concurrently computes its h2(t-1)*W_hh2 partial.
//   barrier1 (all 256 WGs, monotonic device-scope counter)
//   phase3: L2 adds h1(t)*W_ih2, reduces, tanh -> h2(t), writes out(t)
//           partials via fp32 atomicAdd.
//   barrier2 (L2's 192 WGs only) -- L1 already runs step t+1 (overlap).
// ---------------------------------------------------------------------------

typedef short s16x8 __attribute__((ext_vector_type(8)));   // 8 bf16 in 4 VGPRs
typedef float fx4   __attribute__((ext_vector_type(4)));   // MFMA C/D

#define NWG   256
#define NL1   64
#define NL2   192
#define T_LEN 1024
#define H     768
#define BB    128

// ws layout (bytes)
#define CTR1_OFF  0
#define CTR2_OFF  128
#define HBUF_OFF  256
#define HBYTES    (BB * H * 2)               // one bf16 [128][768] buffer
// h1_hi[2], h1_lo[2], h2_hi, h2_lo
#define H1HI(buf) (HBUF_OFF + (buf) * HBYTES)
#define H1LO(buf) (HBUF_OFF + 2 * HBYTES + (buf) * HBYTES)
#define H2HI      (HBUF_OFF + 4 * HBYTES)
#define H2LO      (HBUF_OFF + 5 * HBYTES)
#define WS_ZERO_BYTES (HBUF_OFF + 6 * HBYTES)

__device__ __forceinline__ unsigned short f2bf(float x) {
    unsigned u = __float_as_uint(x);
    unsigned r = (u + 0x7FFFu + ((u >> 16) & 1u)) >> 16;   // RNE
    return (unsigned short)r;
}
__device__ __forceinline__ float bf2f(unsigned short b) {
    return __uint_as_float(((unsigned)b) << 16);
}

__device__ __forceinline__ fx4 mfma16(s16x8 a, s16x8 b, fx4 c) {
    return __builtin_amdgcn_mfma_f32_16x16x32_bf16(a, b, c, 0, 0, 0);
}

// Build one B-fragment pair (hi,lo) for mfma_f32_16x16x32_bf16 from fp32 W.
// B layout: lane l holds B[k=(l>>4)*8+j][col=l&15] = W[col][k...k+7].
__device__ __forceinline__ void load_wfrag(const float* __restrict__ W,
                                           int col, int kk, s16x8& hi, s16x8& lo) {
    const float* p = W + (long)col * H + kk;
#pragma unroll
    for (int j = 0; j < 8; j++) {
        float w = p[j];
        unsigned short h = f2bf(w);
        float r = w - bf2f(h);
        hi[j] = (short)h;
        lo[j] = (short)f2bf(r);
    }
}

// A-fragment: lane l holds A[row=l&15][k=(l>>4)*8+j] -> 16B contiguous load.
__device__ __forceinline__ s16x8 load_afrag(const unsigned short* Hb, int row, int kk) {
    return *reinterpret_cast<const s16x8*>(Hb + (long)row * H + kk);
}

// Device-scope grid barrier, monotonic counter (zeroed by host memset each call).
__device__ __forceinline__ void grid_barrier(unsigned* ctr, unsigned target) {
    __syncthreads();
    if (threadIdx.x == 0) {
        __threadfence();  // release: make this WG's global stores agent-visible
        __hip_atomic_fetch_add(ctr, 1u, __ATOMIC_RELAXED, __HIP_MEMORY_SCOPE_AGENT);
        long spin = 0;
        while (__hip_atomic_load(ctr, __ATOMIC_RELAXED, __HIP_MEMORY_SCOPE_AGENT) < target) {
            __builtin_amdgcn_s_sleep(1);
            if (++spin > (1L << 22)) break;  // failsafe, should never trigger
        }
        __threadfence();  // acquire: invalidate stale cache lines
    }
    __syncthreads();
}

__global__ __launch_bounds__(256, 1) void rnn_persist(
    const float* __restrict__ x,
    const float* __restrict__ Wih1, const float* __restrict__ Whh1,
    const float* __restrict__ bih1, const float* __restrict__ bhh1,
    const float* __restrict__ Wih2, const float* __restrict__ Whh2,
    const float* __restrict__ bih2, const float* __restrict__ bhh2,
    const float* __restrict__ Wlin, const float* __restrict__ blin,
    float* __restrict__ out, unsigned char* __restrict__ ws)
{
    const int wg = blockIdx.x;
    const int tid = threadIdx.x;
    const int lane = tid & 63;
    const int w = tid >> 6;          // wave 0..3, owns K range [w*192, w*192+192)
    const int l15 = lane & 15;
    const int lk8 = (lane >> 4) * 8; // k sub-offset within 32-wide k-step

    unsigned* ctr1 = (unsigned*)(ws + CTR1_OFF);
    unsigned* ctr2 = (unsigned*)(ws + CTR2_OFF);
    unsigned short* h1hi[2] = {(unsigned short*)(ws + H1HI(0)), (unsigned short*)(ws + H1HI(1))};
    unsigned short* h1lo[2] = {(unsigned short*)(ws + H1LO(0)), (unsigned short*)(ws + H1LO(1))};
    unsigned short* h2hi = (unsigned short*)(ws + H2HI);
    unsigned short* h2lo = (unsigned short*)(ws + H2LO);

    __shared__ float red[4][32][49];   // [wave][row][col(+pad)]

    const int kb0 = w * 192;

    if (wg < NL1) {
        // ------------------------- Layer-1 workgroup -------------------------
        const int rg = wg >> 4, cg = wg & 15;
        const int row0 = rg * 32, col0 = cg * 48;

        // Persistent W_hh1 B-fragments: [kstep 0..5][ntile 0..2], hi+lo.
        s16x8 whi[6][3], wlo[6][3];
#pragma unroll
        for (int ks = 0; ks < 6; ks++)
#pragma unroll
            for (int nt = 0; nt < 3; nt++)
                load_wfrag(Whh1, col0 + nt * 16 + l15, kb0 + ks * 32 + lk8,
                           whi[ks][nt], wlo[ks][nt]);

        // Per-thread epilogue constants: 6 output elems each (32x48 tile).
        float bs[6], wi0[6], wi1[6];
        int rr[6], cc[6];
#pragma unroll
        for (int e = 0; e < 6; e++) {
            int idx = tid + e * 256;
            rr[e] = idx / 48; cc[e] = idx % 48;
            int c = col0 + cc[e];
            bs[e] = bih1[c] + bhh1[c];
            wi0[e] = Wih1[c * 2 + 0];
            wi1[e] = Wih1[c * 2 + 1];
        }

        for (int t = 0; t < T_LEN; t++) {
            const int cur = t & 1, nxt = cur ^ 1;
            const unsigned short* Hh = h1hi[cur];
            const unsigned short* Hl = h1lo[cur];

            fx4 z = {0.f, 0.f, 0.f, 0.f};
            fx4 acc[2][3];
#pragma unroll
            for (int mt = 0; mt < 2; mt++)
#pragma unroll
                for (int nt = 0; nt < 3; nt++) acc[mt][nt] = z;

#pragma unroll
            for (int ks = 0; ks < 6; ks++) {
                const int kk = kb0 + ks * 32 + lk8;
                s16x8 ah0 = load_afrag(Hh, row0 + l15, kk);
                s16x8 ah1 = load_afrag(Hh, row0 + 16 + l15, kk);
                s16x8 al0 = load_afrag(Hl, row0 + l15, kk);
                s16x8 al1 = load_afrag(Hl, row0 + 16 + l15, kk);
#pragma unroll
                for (int nt = 0; nt < 3; nt++) {
                    acc[0][nt] = mfma16(ah0, whi[ks][nt], acc[0][nt]);
                    acc[1][nt] = mfma16(ah1, whi[ks][nt], acc[1][nt]);
                    acc[0][nt] = mfma16(ah0, wlo[ks][nt], acc[0][nt]);
                    acc[1][nt] = mfma16(ah1, wlo[ks][nt], acc[1][nt]);
                    acc[0][nt] = mfma16(al0, whi[ks][nt], acc[0][nt]);
                    acc[1][nt] = mfma16(al1, whi[ks][nt], acc[1][nt]);
                }
            }

            // K-split partial reduce through LDS.
#pragma unroll
            for (int mt = 0; mt < 2; mt++)
#pragma unroll
                for (int nt = 0; nt < 3; nt++)
#pragma unroll
                    for (int i = 0; i < 4; i++)
                        red[w][mt * 16 + (lane >> 4) * 4 + i][nt * 16 + l15] = acc[mt][nt][i];
            __syncthreads();

            unsigned short* Dh = h1hi[nxt];
            unsigned short* Dl = h1lo[nxt];
#pragma unroll
            for (int e = 0; e < 6; e++) {
                int r = rr[e], c = cc[e];
                float v = red[0][r][c] + red[1][r][c] + red[2][r][c] + red[3][r][c];
                int b = row0 + r;
                v += x[b * 2048 + t] * wi0[e] + x[b * 2048 + 1024 + t] * wi1[e] + bs[e];
                v = tanhf(v);
                unsigned short hb = f2bf(v);
                Dh[b * H + col0 + c] = hb;
                Dl[b * H + col0 + c] = f2bf(v - bf2f(hb));
            }
            grid_barrier(ctr1, (unsigned)(t + 1) * NWG);
            // L1 does not wait on barrier2: it can start step t+1 immediately.
        }
    } else {
        // ------------------------- Layer-2 workgroup -------------------------
        const int q = wg - NL1;
        const int rg = q / 48, cg = q % 48;
        const int row0 = rg * 32, col0 = cg * 16;

        s16x8 ghi[6], glo[6];   // W_hh2 fragments
        s16x8 ihi[6], ilo[6];   // W_ih2 fragments
#pragma unroll
        for (int ks = 0; ks < 6; ks++) {
            load_wfrag(Whh2, col0 + l15, kb0 + ks * 32 + lk8, ghi[ks], glo[ks]);
            load_wfrag(Wih2, col0 + l15, kb0 + ks * 32 + lk8, ihi[ks], ilo[ks]);
        }

        float bs2[2];
#pragma unroll
        for (int e = 0; e < 2; e++) {
            int idx = tid + e * 256;
            bs2[e] = bih2[col0 + (idx & 15)] + bhh2[col0 + (idx & 15)];
        }
        // out epilogue: threads 0..63 -> (row ro, out-channel oo)
        const int ro = tid >> 1, oo = tid & 1;
        float wl[16];
        if (tid < 64) {
#pragma unroll
            for (int c = 0; c < 16; c++) wl[c] = Wlin[oo * H + col0 + c];
        }

        for (int t = 0; t < T_LEN; t++) {
            const int nxt = (t & 1) ^ 1;

            fx4 z = {0.f, 0.f, 0.f, 0.f};
            fx4 acc[2] = {z, z};

            // phase 1: h2(t-1) @ W_hh2^T  (independent of L1's current work)
#pragma unroll
            for (int ks = 0; ks < 6; ks++) {
                const int kk = kb0 + ks * 32 + lk8;
                s16x8 ah0 = load_afrag(h2hi, row0 + l15, kk);
                s16x8 ah1 = load_afrag(h2hi, row0 + 16 + l15, kk);
                s16x8 al0 = load_afrag(h2lo, row0 + l15, kk);
                s16x8 al1 = load_afrag(h2lo, row0 + 16 + l15, kk);
                acc[0] = mfma16(ah0, ghi[ks], acc[0]);
                acc[1] = mfma16(ah1, ghi[ks], acc[1]);
                acc[0] = mfma16(ah0, glo[ks], acc[0]);
                acc[1] = mfma16(ah1, glo[ks], acc[1]);
                acc[0] = mfma16(al0, ghi[ks], acc[0]);
                acc[1] = mfma16(al1, ghi[ks], acc[1]);
            }

            grid_barrier(ctr1, (unsigned)(t + 1) * NWG);   // wait for h1(t)

            // phase 3: += h1(t) @ W_ih2^T
            const unsigned short* Hh = h1hi[nxt];
            const unsigned short* Hl = h1lo[nxt];
#pragma unroll
            for (int ks = 0; ks < 6; ks++) {
                const int kk = kb0 + ks * 32 + lk8;
                s16x8 ah0 = load_afrag(Hh, row0 + l15, kk);
                s16x8 ah1 = load_afrag(Hh, row0 + 16 + l15, kk);
                s16x8 al0 = load_afrag(Hl, row0 + l15, kk);
                s16x8 al1 = load_afrag(Hl, row0 + 16 + l15, kk);
                acc[0] = mfma16(ah0, ihi[ks], acc[0]);
                acc[1] = mfma16(ah1, ihi[ks], acc[1]);
                acc[0] = mfma16(ah0, ilo[ks], acc[0]);
                acc[1] = mfma16(ah1, ilo[ks], acc[1]);
                acc[0] = mfma16(al0, ihi[ks], acc[0]);
                acc[1] = mfma16(al1, ihi[ks], acc[1]);
            }

#pragma unroll
            for (int mt = 0; mt < 2; mt++)
#pragma unroll
                for (int i = 0; i < 4; i++)
                    red[w][mt * 16 + (lane >> 4) * 4 + i][l15] = acc[mt][i];
            __syncthreads();

#pragma unroll
            for (int e = 0; e < 2; e++) {
                int idx = tid + e * 256;
                int r = idx >> 4, c = idx & 15;
                float v = red[0][r][c] + red[1][r][c] + red[2][r][c] + red[3][r][c] + bs2[e];
                v = tanhf(v);
                int b = row0 + r;
                unsigned short hb = f2bf(v);
                h2hi[b * H + col0 + c] = hb;
                h2lo[b * H + col0 + c] = f2bf(v - bf2f(hb));
                red[0][r][c] = v;   // element-owned overwrite, reused for out
            }
            __syncthreads();

            if (tid < 64) {
                float s = 0.f;
#pragma unroll
                for (int c = 0; c < 16; c++) s += red[0][ro][c] * wl[c];
                if (cg == 0) s += blin[oo];
                atomicAdd(out + (row0 + ro) * 2048 + oo * 1024 + t, s);
            }

            grid_barrier(ctr2, (unsigned)(t + 1) * NL2);   // L2-only sync for h2
        }
    }
}

extern "C" void kernel_launch(void* const* d_in, const int* in_sizes, int n_in,
                              void* d_out, int out_size, void* d_ws, size_t ws_size,
                              hipStream_t stream) {
    const float* x    = (const float*)d_in[0];
    const float* Wih1 = (const float*)d_in[1];
    const float* Whh1 = (const float*)d_in[2];
    const float* bih1 = (const float*)d_in[3];
    const float* bhh1 = (const float*)d_in[4];
    const float* Wih2 = (const float*)d_in[5];
    const float* Whh2 = (const float*)d_in[6];
    const float* bih2 = (const float*)d_in[7];
    const float* bhh2 = (const float*)d_in[8];
    const float* Wlin = (const float*)d_in[9];
    const float* blin = (const float*)d_in[10];
    // d_in[11] = future (== 0)

    // Zero barrier counters + h-state (initial h = 0) + output (atomicAdd target).
    hipMemsetAsync(d_ws, 0, WS_ZERO_BYTES, stream);
    hipMemsetAsync(d_out, 0, (size_t)out_size * sizeof(float), stream);

    rnn_persist<<<NWG, 256, 0, stream>>>(x, Wih1, Whh1, bih1, bhh1,
                                         Wih2, Whh2, bih2, bhh2,
                                         Wlin, blin, (float*)d_out,
                                         (unsigned char*)d_ws);
}

// Round 2
// 20416.096 us; speedup vs baseline: 1.9484x; 1.9484x over previous
//
#include <hip/hip_runtime.h>
#include <math.h>

// ---------------------------------------------------------------------------
// 2-layer tanh RNN scan, B=128, T=1024, H=768.  Persistent kernel, 256 WGs
// (1/CU).  Round-2 changes vs round-1:
//  * Fence-free grid barrier: cross-WG data written with device-coherent
//    write-through stores (atomic relaxed agent => global_store sc0 sc1), so
//    release = s_waitcnt vmcnt(0) + atomic arrival (NO buffer_wbl2).
//    Acquire = one agent acquire fence (buffer_inv, no writeback) per WG.
//  * out atomicAdd storm removed: L2 WGs store per-cg partials to ws; L1 WGs
//    (which have schedule slack) shuffle-reduce them one step behind.
//  * Epilogues remapped column-contiguous so all coherent stores are u32.
// Numerics unchanged from the passing round-1 kernel (bf16 hi/lo pairs,
// 3-product MFMA, fp32 accumulate).
// ---------------------------------------------------------------------------

typedef short s16x8 __attribute__((ext_vector_type(8)));   // 8 bf16 in 4 VGPRs
typedef float fx4   __attribute__((ext_vector_type(4)));   // MFMA C/D

#define NWG   256
#define NL1   64
#define NL2   192
#define T_LEN 1024
#define H     768
#define BB    128

// ws layout (bytes)
#define CTR1_OFF  0
#define CTR2_OFF  128
#define HBUF_OFF  256
#define HBYTES    (BB * H * 2)               // one bf16 [128][768] buffer
#define H1HI(buf) (HBUF_OFF + (buf) * HBYTES)
#define H1LO(buf) (HBUF_OFF + 2 * HBYTES + (buf) * HBYTES)
#define H2HI      (HBUF_OFF + 4 * HBYTES)
#define H2LO      (HBUF_OFF + 5 * HBYTES)
#define PBUF_OFF  (HBUF_OFF + 6 * HBYTES)    // float P[2][128][2][48]
#define WS_ZERO_BYTES PBUF_OFF

__device__ __forceinline__ unsigned short f2bf(float x) {
    unsigned u = __float_as_uint(x);
    unsigned r = (u + 0x7FFFu + ((u >> 16) & 1u)) >> 16;   // RNE
    return (unsigned short)r;
}
__device__ __forceinline__ float bf2f(unsigned short b) {
    return __uint_as_float(((unsigned)b) << 16);
}

__device__ __forceinline__ fx4 mfma16(s16x8 a, s16x8 b, fx4 c) {
    return __builtin_amdgcn_mfma_f32_16x16x32_bf16(a, b, c, 0, 0, 0);
}

// Device-coherent write-through store (global_store_dword sc0 sc1).
__device__ __forceinline__ void st_agent_u32(unsigned* p, unsigned v) {
    __hip_atomic_store(p, v, __ATOMIC_RELAXED, __HIP_MEMORY_SCOPE_AGENT);
}

// Build one B-fragment pair (hi,lo) for mfma_f32_16x16x32_bf16 from fp32 W.
__device__ __forceinline__ void load_wfrag(const float* __restrict__ W,
                                           int col, int kk, s16x8& hi, s16x8& lo) {
    const float* p = W + (long)col * H + kk;
#pragma unroll
    for (int j = 0; j < 8; j++) {
        float w = p[j];
        unsigned short h = f2bf(w);
        float r = w - bf2f(h);
        hi[j] = (short)h;
        lo[j] = (short)f2bf(r);
    }
}

__device__ __forceinline__ s16x8 load_afrag(const unsigned short* Hb, int row, int kk) {
    return *reinterpret_cast<const s16x8*>(Hb + (long)row * H + kk);
}

// Fence-free grid barrier: per-thread vmcnt drain, one arrival per WG,
// acquire (buffer_inv, no writeback) after detection.
__device__ __forceinline__ void gbar(unsigned* ctr, unsigned target) {
    asm volatile("s_waitcnt vmcnt(0)" ::: "memory");   // my coherent stores retired
    __syncthreads();
    if (threadIdx.x == 0) {
        __hip_atomic_fetch_add(ctr, 1u, __ATOMIC_RELAXED, __HIP_MEMORY_SCOPE_AGENT);
        long spin = 0;
        while (__hip_atomic_load(ctr, __ATOMIC_RELAXED, __HIP_MEMORY_SCOPE_AGENT) < target) {
            __builtin_amdgcn_s_sleep(2);
            if (++spin > (1L << 22)) break;            // failsafe
        }
        __builtin_amdgcn_fence(__ATOMIC_ACQUIRE, "agent");  // buffer_inv only
    }
    __syncthreads();
}

// Wait-only (no arrival) variant.
__device__ __forceinline__ void gwait(unsigned* ctr, unsigned target) {
    if (threadIdx.x == 0) {
        long spin = 0;
        while (__hip_atomic_load(ctr, __ATOMIC_RELAXED, __HIP_MEMORY_SCOPE_AGENT) < target) {
            __builtin_amdgcn_s_sleep(2);
            if (++spin > (1L << 22)) break;
        }
        __builtin_amdgcn_fence(__ATOMIC_ACQUIRE, "agent");
    }
    __syncthreads();
}

__global__ __launch_bounds__(256, 1) void rnn_persist(
    const float* __restrict__ x,
    const float* __restrict__ Wih1, const float* __restrict__ Whh1,
    const float* __restrict__ bih1, const float* __restrict__ bhh1,
    const float* __restrict__ Wih2, const float* __restrict__ Whh2,
    const float* __restrict__ bih2, const float* __restrict__ bhh2,
    const float* __restrict__ Wlin, const float* __restrict__ blin,
    float* __restrict__ out, unsigned char* __restrict__ ws)
{
    const int wg = blockIdx.x;
    const int tid = threadIdx.x;
    const int lane = tid & 63;
    const int w = tid >> 6;          // wave 0..3, owns K range [w*192, +192)
    const int l15 = lane & 15;
    const int lk8 = (lane >> 4) * 8;

    unsigned* ctr1 = (unsigned*)(ws + CTR1_OFF);
    unsigned* ctr2 = (unsigned*)(ws + CTR2_OFF);
    unsigned short* h1hi[2] = {(unsigned short*)(ws + H1HI(0)), (unsigned short*)(ws + H1HI(1))};
    unsigned short* h1lo[2] = {(unsigned short*)(ws + H1LO(0)), (unsigned short*)(ws + H1LO(1))};
    unsigned short* h2hi = (unsigned short*)(ws + H2HI);
    unsigned short* h2lo = (unsigned short*)(ws + H2LO);
    float* Pbuf = (float*)(ws + PBUF_OFF);   // [2][128][2][48]

    __shared__ float red[4][32][49];   // [wave][row][col(+pad)]

    const int kb0 = w * 192;

    if (wg < NL1) {
        // ------------------------- Layer-1 workgroup -------------------------
        const int rg = wg >> 4, cg = wg & 15;
        const int row0 = rg * 32, col0 = cg * 48;

        s16x8 whi[6][3], wlo[6][3];
#pragma unroll
        for (int ks = 0; ks < 6; ks++)
#pragma unroll
            for (int nt = 0; nt < 3; nt++)
                load_wfrag(Whh1, col0 + nt * 16 + l15, kb0 + ks * 32 + lk8,
                           whi[ks][nt], wlo[ks][nt]);

        // Epilogue ownership: one row, 6 consecutive cols per thread.
        const int er = tid >> 3;                // 0..31
        const int ec0 = (tid & 7) * 6;          // 0,6,...,42
        const int eb = row0 + er;
        float bs[6], wi0[6], wi1[6];
#pragma unroll
        for (int j = 0; j < 6; j++) {
            int c = col0 + ec0 + j;
            bs[j] = bih1[c] + bhh1[c];
            wi0[j] = Wih1[c * 2 + 0];
            wi1[j] = Wih1[c * 2 + 1];
        }
        // out-reduction constants (wave 0 only uses them)
        const int oq = tid >> 4, oj = tid & 15;          // tid<64
        const int ov = wg * 4 + oq;                      // out value 0..255
        const int ob = ov >> 1, oo = ov & 1;
        const float blv = blin[oo];

        for (int t = 0; t < T_LEN; t++) {
            const int cur = t & 1, nxt = cur ^ 1;
            const unsigned short* Hh = h1hi[cur];
            const unsigned short* Hl = h1lo[cur];

            fx4 z = {0.f, 0.f, 0.f, 0.f};
            fx4 acc[2][3];
#pragma unroll
            for (int mt = 0; mt < 2; mt++)
#pragma unroll
                for (int nt = 0; nt < 3; nt++) acc[mt][nt] = z;

#pragma unroll
            for (int ks = 0; ks < 6; ks++) {
                const int kk = kb0 + ks * 32 + lk8;
                s16x8 ah0 = load_afrag(Hh, row0 + l15, kk);
                s16x8 ah1 = load_afrag(Hh, row0 + 16 + l15, kk);
                s16x8 al0 = load_afrag(Hl, row0 + l15, kk);
                s16x8 al1 = load_afrag(Hl, row0 + 16 + l15, kk);
#pragma unroll
                for (int nt = 0; nt < 3; nt++) {
                    acc[0][nt] = mfma16(ah0, whi[ks][nt], acc[0][nt]);
                    acc[1][nt] = mfma16(ah1, whi[ks][nt], acc[1][nt]);
                    acc[0][nt] = mfma16(ah0, wlo[ks][nt], acc[0][nt]);
                    acc[1][nt] = mfma16(ah1, wlo[ks][nt], acc[1][nt]);
                    acc[0][nt] = mfma16(al0, whi[ks][nt], acc[0][nt]);
                    acc[1][nt] = mfma16(al1, whi[ks][nt], acc[1][nt]);
                }
            }

#pragma unroll
            for (int mt = 0; mt < 2; mt++)
#pragma unroll
                for (int nt = 0; nt < 3; nt++)
#pragma unroll
                    for (int i = 0; i < 4; i++)
                        red[w][mt * 16 + (lane >> 4) * 4 + i][nt * 16 + l15] = acc[mt][nt][i];
            __syncthreads();

            // Epilogue: 6 consecutive cols of one row -> 3+3 coherent u32 stores.
            float x0 = x[eb * 2048 + t];
            float x1 = x[eb * 2048 + 1024 + t];
            unsigned hw[3], lw[3];
#pragma unroll
            for (int jj = 0; jj < 3; jj++) {
                unsigned hp = 0, lp = 0;
#pragma unroll
                for (int k = 0; k < 2; k++) {
                    int j = jj * 2 + k;
                    int c = ec0 + j;
                    float v = red[0][er][c] + red[1][er][c] + red[2][er][c] + red[3][er][c];
                    v += x0 * wi0[j] + x1 * wi1[j] + bs[j];
                    v = tanhf(v);
                    unsigned short hb = f2bf(v);
                    unsigned short lb = f2bf(v - bf2f(hb));
                    hp |= ((unsigned)hb) << (16 * k);
                    lp |= ((unsigned)lb) << (16 * k);
                }
                hw[jj] = hp; lw[jj] = lp;
            }
            unsigned* Dh = (unsigned*)(h1hi[nxt] + (long)eb * H + col0 + ec0);
            unsigned* Dl = (unsigned*)(h1lo[nxt] + (long)eb * H + col0 + ec0);
            st_agent_u32(Dh + 0, hw[0]); st_agent_u32(Dh + 1, hw[1]); st_agent_u32(Dh + 2, hw[2]);
            st_agent_u32(Dl + 0, lw[0]); st_agent_u32(Dl + 1, lw[1]); st_agent_u32(Dl + 2, lw[2]);

            gbar(ctr1, (unsigned)(t + 1) * NWG);

            // Off-critical-path: reduce out(t-1) partials (wave 0, uniform).
            if (t >= 1 && tid < 64) {
                const float* Pp = Pbuf + (((long)((t - 1) & 1) * BB + ob) * 2 + oo) * 48;
                float p = Pp[oj] + Pp[oj + 16] + Pp[oj + 32];
                p += __shfl_xor(p, 8, 16);
                p += __shfl_xor(p, 4, 16);
                p += __shfl_xor(p, 2, 16);
                p += __shfl_xor(p, 1, 16);
                if (oj == 0) out[ob * 2048 + oo * 1024 + (t - 1)] = p + blv;
            }
        }
        // Final step's out values.
        gwait(ctr2, (unsigned)T_LEN * NL2);
        if (tid < 64) {
            const float* Pp = Pbuf + (((long)((T_LEN - 1) & 1) * BB + ob) * 2 + oo) * 48;
            float p = Pp[oj] + Pp[oj + 16] + Pp[oj + 32];
            p += __shfl_xor(p, 8, 16);
            p += __shfl_xor(p, 4, 16);
            p += __shfl_xor(p, 2, 16);
            p += __shfl_xor(p, 1, 16);
            if (oj == 0) out[ob * 2048 + oo * 1024 + (T_LEN - 1)] = p + blv;
        }
    } else {
        // ------------------------- Layer-2 workgroup -------------------------
        const int q = wg - NL1;
        const int rg = q / 48, cg = q % 48;
        const int row0 = rg * 32, col0 = cg * 16;

        s16x8 ghi[6], glo[6];   // W_hh2
        s16x8 ihi[6], ilo[6];   // W_ih2
#pragma unroll
        for (int ks = 0; ks < 6; ks++) {
            load_wfrag(Whh2, col0 + l15, kb0 + ks * 32 + lk8, ghi[ks], glo[ks]);
            load_wfrag(Wih2, col0 + l15, kb0 + ks * 32 + lk8, ihi[ks], ilo[ks]);
        }

        // Epilogue ownership: one row, 2 consecutive cols per thread.
        const int er = tid >> 3;            // 0..31
        const int ec0 = (tid & 7) * 2;      // 0,2,...,14
        const int eb = row0 + er;
        const float bsA = bih2[col0 + ec0] + bhh2[col0 + ec0];
        const float bsB = bih2[col0 + ec0 + 1] + bhh2[col0 + ec0 + 1];

        const int ro = tid >> 1, oo = tid & 1;   // tid<64: P-partial dot
        float wl[16];
        if (tid < 64) {
#pragma unroll
            for (int c = 0; c < 16; c++) wl[c] = Wlin[oo * H + col0 + c];
        }

        for (int t = 0; t < T_LEN; t++) {
            const int nxt = (t & 1) ^ 1;

            fx4 z = {0.f, 0.f, 0.f, 0.f};
            fx4 acc[2] = {z, z};

            // phase 1: h2(t-1) @ W_hh2^T  (overlaps L1's h1(t) compute)
#pragma unroll
            for (int ks = 0; ks < 6; ks++) {
                const int kk = kb0 + ks * 32 + lk8;
                s16x8 ah0 = load_afrag(h2hi, row0 + l15, kk);
                s16x8 ah1 = load_afrag(h2hi, row0 + 16 + l15, kk);
                s16x8 al0 = load_afrag(h2lo, row0 + l15, kk);
                s16x8 al1 = load_afrag(h2lo, row0 + 16 + l15, kk);
                acc[0] = mfma16(ah0, ghi[ks], acc[0]);
                acc[1] = mfma16(ah1, ghi[ks], acc[1]);
                acc[0] = mfma16(ah0, glo[ks], acc[0]);
                acc[1] = mfma16(ah1, glo[ks], acc[1]);
                acc[0] = mfma16(al0, ghi[ks], acc[0]);
                acc[1] = mfma16(al1, ghi[ks], acc[1]);
            }

            gbar(ctr1, (unsigned)(t + 1) * NWG);   // wait for h1(t)

            // phase 3: += h1(t) @ W_ih2^T
            const unsigned short* Hh = h1hi[nxt];
            const unsigned short* Hl = h1lo[nxt];
#pragma unroll
            for (int ks = 0; ks < 6; ks++) {
                const int kk = kb0 + ks * 32 + lk8;
                s16x8 ah0 = load_afrag(Hh, row0 + l15, kk);
                s16x8 ah1 = load_afrag(Hh, row0 + 16 + l15, kk);
                s16x8 al0 = load_afrag(Hl, row0 + l15, kk);
                s16x8 al1 = load_afrag(Hl, row0 + 16 + l15, kk);
                acc[0] = mfma16(ah0, ihi[ks], acc[0]);
                acc[1] = mfma16(ah1, ihi[ks], acc[1]);
                acc[0] = mfma16(ah0, ilo[ks], acc[0]);
                acc[1] = mfma16(ah1, ilo[ks], acc[1]);
                acc[0] = mfma16(al0, ihi[ks], acc[0]);
                acc[1] = mfma16(al1, ihi[ks], acc[1]);
            }

#pragma unroll
            for (int mt = 0; mt < 2; mt++)
#pragma unroll
                for (int i = 0; i < 4; i++)
                    red[w][mt * 16 + (lane >> 4) * 4 + i][l15] = acc[mt][i];
            __syncthreads();

            // h2 epilogue: 2 cols of one row -> 2 coherent u32 stores.
            float v0 = red[0][er][ec0] + red[1][er][ec0] + red[2][er][ec0] + red[3][er][ec0] + bsA;
            float v1 = red[0][er][ec0 + 1] + red[1][er][ec0 + 1] + red[2][er][ec0 + 1] + red[3][er][ec0 + 1] + bsB;
            v0 = tanhf(v0); v1 = tanhf(v1);
            unsigned short h0 = f2bf(v0), h1b = f2bf(v1);
            unsigned hp = ((unsigned)h0) | (((unsigned)h1b) << 16);
            unsigned lp = ((unsigned)f2bf(v0 - bf2f(h0))) | (((unsigned)f2bf(v1 - bf2f(h1b))) << 16);
            st_agent_u32((unsigned*)(h2hi + (long)eb * H + col0 + ec0), hp);
            st_agent_u32((unsigned*)(h2lo + (long)eb * H + col0 + ec0), lp);
            red[0][er][ec0] = v0;
            red[0][er][ec0 + 1] = v1;
            __syncthreads();

            // per-cg out partial -> P (one owner per word, coherent store)
            if (tid < 64) {
                float s = 0.f;
#pragma unroll
                for (int c = 0; c < 16; c++) s += red[0][ro][c] * wl[c];
                unsigned* pp = (unsigned*)&Pbuf[(((long)(t & 1) * BB + row0 + ro) * 2 + oo) * 48 + cg];
                st_agent_u32(pp, __float_as_uint(s));
            }

            gbar(ctr2, (unsigned)(t + 1) * NL2);   // L2-only sync for h2
        }
    }
}

extern "C" void kernel_launch(void* const* d_in, const int* in_sizes, int n_in,
                              void* d_out, int out_size, void* d_ws, size_t ws_size,
                              hipStream_t stream) {
    const float* x    = (const float*)d_in[0];
    const float* Wih1 = (const float*)d_in[1];
    const float* Whh1 = (const float*)d_in[2];
    const float* bih1 = (const float*)d_in[3];
    const float* bhh1 = (const float*)d_in[4];
    const float* Wih2 = (const float*)d_in[5];
    const float* Whh2 = (const float*)d_in[6];
    const float* bih2 = (const float*)d_in[7];
    const float* bhh2 = (const float*)d_in[8];
    const float* Wlin = (const float*)d_in[9];
    const float* blin = (const float*)d_in[10];

    // Zero barrier counters + h-state (initial h = 0). out fully overwritten.
    hipMemsetAsync(d_ws, 0, WS_ZERO_BYTES, stream);

    rnn_persist<<<NWG, 256, 0, stream>>>(x, Wih1, Whh1, bih1, bhh1,
                                         Wih2, Whh2, bih2, bhh2,
                                         Wlin, blin, (float*)d_out,
                                         (unsigned char*)d_ws);
}

// Round 3
// 13162.115 us; speedup vs baseline: 3.0222x; 1.5511x over previous
//
#include <hip/hip_runtime.h>
#include <math.h>

// ---------------------------------------------------------------------------
// 2-layer tanh RNN scan, B=128, T=1024, H=768.  Persistent kernel, 256 WGs
// (1/CU).  Round-3 changes vs round-2 (data path & numerics UNCHANGED):
//  * Barrier arrivals: one coherent store per WG to its OWN flag word
//    (no atomic RMW, no same-line contention).  flagsL1 replicated x4.
//  * Waits: wave-0 polls packed flag arrays with coalesced loads +
//    __shfl_xor min-reduce; thread-0 acquire fence (buffer_inv); syncthreads.
//  * Dependency-minimal waits: L2 phase3 waits only on L1 flags; h2 sync is
//    per-row-group (fan-in 48); h2 double-buffered to make that legal;
//    L1 P-reduce moved before its arrival (closes P anti-dep race).
// ---------------------------------------------------------------------------

typedef short s16x8 __attribute__((ext_vector_type(8)));   // 8 bf16 in 4 VGPRs
typedef float fx4   __attribute__((ext_vector_type(4)));   // MFMA C/D

#define NWG   256
#define NL1   64
#define NL2   192
#define T_LEN 1024
#define H     768
#define BB    128

// ws layout (bytes)
#define FL1_OFF   0                  // 4 replicas x 64 u32 (256B stride)
#define FL2_OFF   1024               // 192 u32
#define FH2_OFF   2048               // 4 rg x 64 u32 (48 used per rg)
#define HBUF_OFF  4096
#define HBYTES    (BB * H * 2)       // one bf16 [128][768] buffer
#define H1HI(b)   (HBUF_OFF + (b) * HBYTES)
#define H1LO(b)   (HBUF_OFF + 2 * HBYTES + (b) * HBYTES)
#define H2HI(b)   (HBUF_OFF + 4 * HBYTES + (b) * HBYTES)
#define H2LO(b)   (HBUF_OFF + 6 * HBYTES + (b) * HBYTES)
#define PBUF_OFF  (HBUF_OFF + 8 * HBYTES)   // float P[2][128][2][48]
#define WS_ZERO_BYTES PBUF_OFF

__device__ __forceinline__ unsigned short f2bf(float x) {
    unsigned u = __float_as_uint(x);
    unsigned r = (u + 0x7FFFu + ((u >> 16) & 1u)) >> 16;   // RNE
    return (unsigned short)r;
}
__device__ __forceinline__ float bf2f(unsigned short b) {
    return __uint_as_float(((unsigned)b) << 16);
}

__device__ __forceinline__ fx4 mfma16(s16x8 a, s16x8 b, fx4 c) {
    return __builtin_amdgcn_mfma_f32_16x16x32_bf16(a, b, c, 0, 0, 0);
}

// Device-coherent write-through store (no dirty L2 lines).
__device__ __forceinline__ void st_agent_u32(unsigned* p, unsigned v) {
    __hip_atomic_store(p, v, __ATOMIC_RELAXED, __HIP_MEMORY_SCOPE_AGENT);
}
__device__ __forceinline__ unsigned ld_flag(unsigned* p) {
    return __hip_atomic_load(p, __ATOMIC_RELAXED, __HIP_MEMORY_SCOPE_AGENT);
}

__device__ __forceinline__ void load_wfrag(const float* __restrict__ W,
                                           int col, int kk, s16x8& hi, s16x8& lo) {
    const float* p = W + (long)col * H + kk;
#pragma unroll
    for (int j = 0; j < 8; j++) {
        float w = p[j];
        unsigned short h = f2bf(w);
        float r = w - bf2f(h);
        hi[j] = (short)h;
        lo[j] = (short)f2bf(r);
    }
}

__device__ __forceinline__ s16x8 load_afrag(const unsigned short* Hb, int row, int kk) {
    return *reinterpret_cast<const s16x8*>(Hb + (long)row * H + kk);
}

__device__ __forceinline__ unsigned wave_min(unsigned v) {
#pragma unroll
    for (int o = 32; o; o >>= 1) {
        unsigned u = (unsigned)__shfl_xor((int)v, o);
        v = v < u ? v : u;
    }
    return v;
}

__device__ __forceinline__ void wait_tail() {
    if (threadIdx.x == 0) __builtin_amdgcn_fence(__ATOMIC_ACQUIRE, "agent");
    __syncthreads();
}

// min over my flagsL1 replica (64 words, one coalesced wave load) >= T
__device__ __forceinline__ void wait_l1(unsigned* rep, unsigned T) {
    if (threadIdx.x < 64) {
        int l = threadIdx.x;
        long spin = 0;
        for (;;) {
            if (wave_min(ld_flag(rep + l)) >= T) break;
            __builtin_amdgcn_s_sleep(2);
            if (++spin > (1L << 18)) break;
        }
    }
    wait_tail();
}

// min over flagsL2 (192 words) >= T
__device__ __forceinline__ void wait_fl2(unsigned* fl2, unsigned T) {
    if (threadIdx.x < 64) {
        int l = threadIdx.x;
        long spin = 0;
        for (;;) {
            unsigned a = ld_flag(fl2 + l);
            unsigned b = ld_flag(fl2 + 64 + l);
            unsigned c = ld_flag(fl2 + 128 + l);
            unsigned m = a < b ? a : b; m = m < c ? m : c;
            if (wave_min(m) >= T) break;
            __builtin_amdgcn_s_sleep(2);
            if (++spin > (1L << 18)) break;
        }
    }
    wait_tail();
}

// min over my row-group's 48 h2 flags >= T
__device__ __forceinline__ void wait_h2rg(unsigned* fh2rg, unsigned T) {
    if (threadIdx.x < 64) {
        int l = threadIdx.x < 48 ? threadIdx.x : 47;
        long spin = 0;
        for (;;) {
            if (wave_min(ld_flag(fh2rg + l)) >= T) break;
            __builtin_amdgcn_s_sleep(2);
            if (++spin > (1L << 18)) break;
        }
    }
    wait_tail();
}

// min over flagsL2 AND all 4 row-groups' h2 flags >= T (final drain)
__device__ __forceinline__ void wait_final(unsigned* fl2, unsigned* fh2, unsigned T) {
    if (threadIdx.x < 64) {
        int l = threadIdx.x;
        int lh = l < 48 ? l : 47;
        long spin = 0;
        for (;;) {
            unsigned m = ld_flag(fl2 + l);
            unsigned b = ld_flag(fl2 + 64 + l);  m = m < b ? m : b;
            b = ld_flag(fl2 + 128 + l);          m = m < b ? m : b;
#pragma unroll
            for (int r = 0; r < 4; r++) {
                b = ld_flag(fh2 + r * 64 + lh);  m = m < b ? m : b;
            }
            if (wave_min(m) >= T) break;
            __builtin_amdgcn_s_sleep(2);
            if (++spin > (1L << 18)) break;
        }
    }
    wait_tail();
}

#define DRAIN_SYNC() do { asm volatile("s_waitcnt vmcnt(0)" ::: "memory"); __syncthreads(); } while (0)

__global__ __launch_bounds__(256, 1) void rnn_persist(
    const float* __restrict__ x,
    const float* __restrict__ Wih1, const float* __restrict__ Whh1,
    const float* __restrict__ bih1, const float* __restrict__ bhh1,
    const float* __restrict__ Wih2, const float* __restrict__ Whh2,
    const float* __restrict__ bih2, const float* __restrict__ bhh2,
    const float* __restrict__ Wlin, const float* __restrict__ blin,
    float* __restrict__ out, unsigned char* __restrict__ ws)
{
    const int wg = blockIdx.x;
    const int tid = threadIdx.x;
    const int lane = tid & 63;
    const int w = tid >> 6;          // wave 0..3, owns K range [w*192, +192)
    const int l15 = lane & 15;
    const int lk8 = (lane >> 4) * 8;

    unsigned* fl1 = (unsigned*)(ws + FL1_OFF);   // 4 replicas x 64
    unsigned* fl2 = (unsigned*)(ws + FL2_OFF);   // 192
    unsigned* fh2 = (unsigned*)(ws + FH2_OFF);   // 4 x 64
    unsigned* myrep = fl1 + (wg & 3) * 64;

    unsigned short* h1hi[2] = {(unsigned short*)(ws + H1HI(0)), (unsigned short*)(ws + H1HI(1))};
    unsigned short* h1lo[2] = {(unsigned short*)(ws + H1LO(0)), (unsigned short*)(ws + H1LO(1))};
    unsigned short* h2hi[2] = {(unsigned short*)(ws + H2HI(0)), (unsigned short*)(ws + H2HI(1))};
    unsigned short* h2lo[2] = {(unsigned short*)(ws + H2LO(0)), (unsigned short*)(ws + H2LO(1))};
    float* Pbuf = (float*)(ws + PBUF_OFF);       // [2][128][2][48]

    __shared__ float red[4][32][49];   // [wave][row][col(+pad)]

    const int kb0 = w * 192;

    if (wg < NL1) {
        // ------------------------- Layer-1 workgroup -------------------------
        const int rg = wg >> 4, cg = wg & 15;
        const int row0 = rg * 32, col0 = cg * 48;

        s16x8 whi[6][3], wlo[6][3];
#pragma unroll
        for (int ks = 0; ks < 6; ks++)
#pragma unroll
            for (int nt = 0; nt < 3; nt++)
                load_wfrag(Whh1, col0 + nt * 16 + l15, kb0 + ks * 32 + lk8,
                           whi[ks][nt], wlo[ks][nt]);

        // Epilogue ownership: one row, 6 consecutive cols per thread.
        const int er = tid >> 3;                // 0..31
        const int ec0 = (tid & 7) * 6;          // 0,6,...,42
        const int eb = row0 + er;
        float bs[6], wi0[6], wi1[6];
#pragma unroll
        for (int j = 0; j < 6; j++) {
            int c = col0 + ec0 + j;
            bs[j] = bih1[c] + bhh1[c];
            wi0[j] = Wih1[c * 2 + 0];
            wi1[j] = Wih1[c * 2 + 1];
        }
        // out-reduction constants (wave 0 only)
        const int oq = tid >> 4, oj = tid & 15;
        const int ov = wg * 4 + oq;
        const int ob = ov >> 1, oo = ov & 1;
        const float blv = blin[oo];

        for (int t = 0; t < T_LEN; t++) {
            const int cur = t & 1, nxt = cur ^ 1;

            if (t > 0) wait_l1(myrep, (unsigned)t);     // h1(t-1) visible

            // x prefetch (read-only, cache-safe)
            float x0 = x[eb * 2048 + t];
            float x1 = x[eb * 2048 + 1024 + t];

            const unsigned short* Hh = h1hi[cur];
            const unsigned short* Hl = h1lo[cur];

            fx4 z = {0.f, 0.f, 0.f, 0.f};
            fx4 acc[2][3];
#pragma unroll
            for (int mt = 0; mt < 2; mt++)
#pragma unroll
                for (int nt = 0; nt < 3; nt++) acc[mt][nt] = z;

#pragma unroll
            for (int ks = 0; ks < 6; ks++) {
                const int kk = kb0 + ks * 32 + lk8;
                s16x8 ah0 = load_afrag(Hh, row0 + l15, kk);
                s16x8 ah1 = load_afrag(Hh, row0 + 16 + l15, kk);
                s16x8 al0 = load_afrag(Hl, row0 + l15, kk);
                s16x8 al1 = load_afrag(Hl, row0 + 16 + l15, kk);
#pragma unroll
                for (int nt = 0; nt < 3; nt++) {
                    acc[0][nt] = mfma16(ah0, whi[ks][nt], acc[0][nt]);
                    acc[1][nt] = mfma16(ah1, whi[ks][nt], acc[1][nt]);
                    acc[0][nt] = mfma16(ah0, wlo[ks][nt], acc[0][nt]);
                    acc[1][nt] = mfma16(ah1, wlo[ks][nt], acc[1][nt]);
                    acc[0][nt] = mfma16(al0, whi[ks][nt], acc[0][nt]);
                    acc[1][nt] = mfma16(al1, whi[ks][nt], acc[1][nt]);
                }
            }

#pragma unroll
            for (int mt = 0; mt < 2; mt++)
#pragma unroll
                for (int nt = 0; nt < 3; nt++)
#pragma unroll
                    for (int i = 0; i < 4; i++)
                        red[w][mt * 16 + (lane >> 4) * 4 + i][nt * 16 + l15] = acc[mt][nt][i];
            __syncthreads();

            // Epilogue values (not stored yet).
            unsigned hw[3], lw[3];
#pragma unroll
            for (int jj = 0; jj < 3; jj++) {
                unsigned hp = 0, lp = 0;
#pragma unroll
                for (int k = 0; k < 2; k++) {
                    int j = jj * 2 + k;
                    int c = ec0 + j;
                    float v = red[0][er][c] + red[1][er][c] + red[2][er][c] + red[3][er][c];
                    v += x0 * wi0[j] + x1 * wi1[j] + bs[j];
                    v = tanhf(v);
                    unsigned short hb = f2bf(v);
                    unsigned short lb = f2bf(v - bf2f(hb));
                    hp |= ((unsigned)hb) << (16 * k);
                    lp |= ((unsigned)lb) << (16 * k);
                }
                hw[jj] = hp; lw[jj] = lp;
            }

            // Anti-dep + P(t-2) gate: all L2 finished phase1(t-1) (=> phase3(t-2)).
            wait_fl2(fl2, (unsigned)t);

            // P-reduce(t-2) BEFORE arrival (writer of P(t) is gated on flagsL1>=t+1).
            if (t >= 2 && tid < 64) {
                const float* Pp = Pbuf + (((long)(t & 1) * BB + ob) * 2 + oo) * 48;
                float p = Pp[oj] + Pp[oj + 16] + Pp[oj + 32];
                p += __shfl_xor(p, 8, 16);
                p += __shfl_xor(p, 4, 16);
                p += __shfl_xor(p, 2, 16);
                p += __shfl_xor(p, 1, 16);
                if (oj == 0) out[ob * 2048 + oo * 1024 + (t - 2)] = p + blv;
            }

            // h1(t) coherent stores.
            unsigned* Dh = (unsigned*)(h1hi[nxt] + (long)eb * H + col0 + ec0);
            unsigned* Dl = (unsigned*)(h1lo[nxt] + (long)eb * H + col0 + ec0);
            st_agent_u32(Dh + 0, hw[0]); st_agent_u32(Dh + 1, hw[1]); st_agent_u32(Dh + 2, hw[2]);
            st_agent_u32(Dl + 0, lw[0]); st_agent_u32(Dl + 1, lw[1]); st_agent_u32(Dl + 2, lw[2]);

            DRAIN_SYNC();
            if (tid == 0) {
#pragma unroll
                for (int r = 0; r < 4; r++) st_agent_u32(fl1 + r * 64 + wg, (unsigned)(t + 1));
            }
        }

        // Final: P(T-2) (needs fl2>=T) and P(T-1) (needs fh2>=T).
        wait_final(fl2, fh2, (unsigned)T_LEN);
        if (tid < 64) {
            {   // t-2 = T-2, parity (T-2)&1 = 0
                const float* Pp = Pbuf + (((long)0 * BB + ob) * 2 + oo) * 48;
                float p = Pp[oj] + Pp[oj + 16] + Pp[oj + 32];
                p += __shfl_xor(p, 8, 16);
                p += __shfl_xor(p, 4, 16);
                p += __shfl_xor(p, 2, 16);
                p += __shfl_xor(p, 1, 16);
                if (oj == 0) out[ob * 2048 + oo * 1024 + (T_LEN - 2)] = p + blv;
            }
            {   // T-1, parity 1
                const float* Pp = Pbuf + (((long)1 * BB + ob) * 2 + oo) * 48;
                float p = Pp[oj] + Pp[oj + 16] + Pp[oj + 32];
                p += __shfl_xor(p, 8, 16);
                p += __shfl_xor(p, 4, 16);
                p += __shfl_xor(p, 2, 16);
                p += __shfl_xor(p, 1, 16);
                if (oj == 0) out[ob * 2048 + oo * 1024 + (T_LEN - 1)] = p + blv;
            }
        }
    } else {
        // ------------------------- Layer-2 workgroup -------------------------
        const int q = wg - NL1;
        const int rg = q / 48, cg = q % 48;
        const int row0 = rg * 32, col0 = cg * 16;

        s16x8 ghi[6], glo[6];   // W_hh2
        s16x8 ihi[6], ilo[6];   // W_ih2
#pragma unroll
        for (int ks = 0; ks < 6; ks++) {
            load_wfrag(Whh2, col0 + l15, kb0 + ks * 32 + lk8, ghi[ks], glo[ks]);
            load_wfrag(Wih2, col0 + l15, kb0 + ks * 32 + lk8, ihi[ks], ilo[ks]);
        }

        const int er = tid >> 3;            // 0..31
        const int ec0 = (tid & 7) * 2;      // 0,2,...,14
        const int eb = row0 + er;
        const float bsA = bih2[col0 + ec0] + bhh2[col0 + ec0];
        const float bsB = bih2[col0 + ec0 + 1] + bhh2[col0 + ec0 + 1];

        const int ro = tid >> 1, oo = tid & 1;   // tid<64: P-partial dot
        float wl[16];
        if (tid < 64) {
#pragma unroll
            for (int c = 0; c < 16; c++) wl[c] = Wlin[oo * H + col0 + c];
        }

        for (int t = 0; t < T_LEN; t++) {
            const int rb = (t + 1) & 1;     // h2(t-1) buffer
            const int wb = t & 1;           // h2(t) buffer
            const int nxt = (t & 1) ^ 1;    // h1(t) buffer

            if (t > 0) wait_h2rg(fh2 + rg * 64, (unsigned)t);   // h2(t-1) ready (my rg)

            const unsigned short* Gh = h2hi[rb];
            const unsigned short* Gl = h2lo[rb];

            fx4 z = {0.f, 0.f, 0.f, 0.f};
            fx4 acc[2] = {z, z};

            // phase 1: h2(t-1) @ W_hh2^T  (overlaps L1's h1(t) compute)
#pragma unroll
            for (int ks = 0; ks < 6; ks++) {
                const int kk = kb0 + ks * 32 + lk8;
                s16x8 ah0 = load_afrag(Gh, row0 + l15, kk);
                s16x8 ah1 = load_afrag(Gh, row0 + 16 + l15, kk);
                s16x8 al0 = load_afrag(Gl, row0 + l15, kk);
                s16x8 al1 = load_afrag(Gl, row0 + 16 + l15, kk);
                acc[0] = mfma16(ah0, ghi[ks], acc[0]);
                acc[1] = mfma16(ah1, ghi[ks], acc[1]);
                acc[0] = mfma16(ah0, glo[ks], acc[0]);
                acc[1] = mfma16(ah1, glo[ks], acc[1]);
                acc[0] = mfma16(al0, ghi[ks], acc[0]);
                acc[1] = mfma16(al1, ghi[ks], acc[1]);
            }

            DRAIN_SYNC();
            if (tid == 0) st_agent_u32(fl2 + q, (unsigned)(t + 1));   // phase1(t) done

            wait_l1(myrep, (unsigned)(t + 1));   // h1(t) ready

            // phase 3: += h1(t) @ W_ih2^T
            const unsigned short* Hh = h1hi[nxt];
            const unsigned short* Hl = h1lo[nxt];
#pragma unroll
            for (int ks = 0; ks < 6; ks++) {
                const int kk = kb0 + ks * 32 + lk8;
                s16x8 ah0 = load_afrag(Hh, row0 + l15, kk);
                s16x8 ah1 = load_afrag(Hh, row0 + 16 + l15, kk);
                s16x8 al0 = load_afrag(Hl, row0 + l15, kk);
                s16x8 al1 = load_afrag(Hl, row0 + 16 + l15, kk);
                acc[0] = mfma16(ah0, ihi[ks], acc[0]);
                acc[1] = mfma16(ah1, ihi[ks], acc[1]);
                acc[0] = mfma16(ah0, ilo[ks], acc[0]);
                acc[1] = mfma16(ah1, ilo[ks], acc[1]);
                acc[0] = mfma16(al0, ihi[ks], acc[0]);
                acc[1] = mfma16(al1, ihi[ks], acc[1]);
            }

#pragma unroll
            for (int mt = 0; mt < 2; mt++)
#pragma unroll
                for (int i = 0; i < 4; i++)
                    red[w][mt * 16 + (lane >> 4) * 4 + i][l15] = acc[mt][i];
            __syncthreads();

            // h2 epilogue: 2 cols of one row -> 2 coherent u32 stores.
            float v0 = red[0][er][ec0] + red[1][er][ec0] + red[2][er][ec0] + red[3][er][ec0] + bsA;
            float v1 = red[0][er][ec0 + 1] + red[1][er][ec0 + 1] + red[2][er][ec0 + 1] + red[3][er][ec0 + 1] + bsB;
            v0 = tanhf(v0); v1 = tanhf(v1);
            unsigned short h0 = f2bf(v0), h1b = f2bf(v1);
            unsigned hp = ((unsigned)h0) | (((unsigned)h1b) << 16);
            unsigned lp = ((unsigned)f2bf(v0 - bf2f(h0))) | (((unsigned)f2bf(v1 - bf2f(h1b))) << 16);
            st_agent_u32((unsigned*)(h2hi[wb] + (long)eb * H + col0 + ec0), hp);
            st_agent_u32((unsigned*)(h2lo[wb] + (long)eb * H + col0 + ec0), lp);
            red[0][er][ec0] = v0;
            red[0][er][ec0 + 1] = v1;
            __syncthreads();

            // per-cg out partial -> P (one owner per word)
            if (tid < 64) {
                float s = 0.f;
#pragma unroll
                for (int c = 0; c < 16; c++) s += red[0][ro][c] * wl[c];
                unsigned* pp = (unsigned*)&Pbuf[(((long)(t & 1) * BB + row0 + ro) * 2 + oo) * 48 + cg];
                st_agent_u32(pp, __float_as_uint(s));
            }

            DRAIN_SYNC();
            if (tid == 0) st_agent_u32(fh2 + rg * 64 + cg, (unsigned)(t + 1));  // h2(t) done
        }
    }
}

extern "C" void kernel_launch(void* const* d_in, const int* in_sizes, int n_in,
                              void* d_out, int out_size, void* d_ws, size_t ws_size,
                              hipStream_t stream) {
    const float* x    = (const float*)d_in[0];
    const float* Wih1 = (const float*)d_in[1];
    const float* Whh1 = (const float*)d_in[2];
    const float* bih1 = (const float*)d_in[3];
    const float* bhh1 = (const float*)d_in[4];
    const float* Wih2 = (const float*)d_in[5];
    const float* Whh2 = (const float*)d_in[6];
    const float* bih2 = (const float*)d_in[7];
    const float* bhh2 = (const float*)d_in[8];
    const float* Wlin = (const float*)d_in[9];
    const float* blin = (const float*)d_in[10];

    // Zero flags + h-state (initial h = 0). P fully written before read;
    // out fully overwritten by L1 reductions.
    hipMemsetAsync(d_ws, 0, WS_ZERO_BYTES, stream);

    rnn_persist<<<NWG, 256, 0, stream>>>(x, Wih1, Whh1, bih1, bhh1,
                                         Wih2, Whh2, bih2, bhh2,
                                         Wlin, blin, (float*)d_out,
                                         (unsigned char*)d_ws);
}

// Round 7
// 10250.792 us; speedup vs baseline: 3.8806x; 1.2840x over previous
//
#include <hip/hip_runtime.h>
#include <math.h>

// ---------------------------------------------------------------------------
// 2-layer tanh RNN scan, B=128, T=1024, H=768.  Persistent kernel, 256 WGs.
// Round-7: r6's 8-group structure with ONLY the r2/r3-PROVEN agent-scope
// coherence primitives (two failed rounds of XCD-local shortcuts abandoned):
//   * cross-WG data writes: __hip_atomic_store relaxed/agent (sc0 sc1
//     write-through, no dirty L2 lines)
//   * flag arrive: same; flag poll: __hip_atomic_load relaxed/agent
//   * after flag detect: ONE agent acquire fence (buffer_inv) by tid 0,
//     then plain (cached) bulk loads  -- exactly r3's passing recipe.
// Structure: B split into 8 independent groups of 16 rows; each group served
// by 32 WGs (8 L1-role: 96 cols each; 24 L2-role: 32 cols each).  Small flag
// fan-ins (8/24/24), double-buffered h1/h2, L2 phase-1 (h2 @ W_hh2) overlaps
// L1's h1 compute.  Numerics: bf16 (hi,lo) pairs, 3-product MFMA, fp32 acc.
// Dependency graph (verified):
//   h1(t) read gate: fL1>=t.  h1(t) overwrite (slot t-2) gate: fP1>=t
//   (L2 flags fP1=t after phase1 of step t-1 => phase3(t-2) reads done;
//   also => P(t-2) fully written).  h2 slot gate: fH2>=t.  P-slot race:
//   L2 writes P(t) only after fL1>=t+1, L1 reads P(t-2) before flagging
//   fL1=t+1.  Final: fH2>=T covers P(T-2), P(T-1).
// ---------------------------------------------------------------------------

typedef short s16x8 __attribute__((ext_vector_type(8)));
typedef float fx4   __attribute__((ext_vector_type(4)));

#define NWG    256
#define T_LEN  1024
#define H      768
#define GROUPS 8
#define GROWS  16
#define NL1R   8

// ws layout (bytes)
#define GRP_BASE   8192
#define GRP_STRIDE 212992
// within a group region:
#define G_FL1 0               // u32[8]   h1-ready flags
#define G_FP1 128             // u32[24]  L2 phase1-done flags
#define G_FH2 256             // u32[24]  h2-ready flags
#define G_PB  512             // float[2][16][2][24] out partials
#define G_HB  8192            // 8 x 24576B: h1hi[2],h1lo[2],h2hi[2],h2lo[2]
#define HB_SZ 24576           // 16*768*2B
#define WS_TOTAL (GRP_BASE + GROUPS * GRP_STRIDE)

__device__ __forceinline__ unsigned short f2bf(float x) {
    unsigned u = __float_as_uint(x);
    unsigned r = (u + 0x7FFFu + ((u >> 16) & 1u)) >> 16;   // RNE
    return (unsigned short)r;
}
__device__ __forceinline__ float bf2f(unsigned short b) {
    return __uint_as_float(((unsigned)b) << 16);
}
__device__ __forceinline__ fx4 mfma16(s16x8 a, s16x8 b, fx4 c) {
    return __builtin_amdgcn_mfma_f32_16x16x32_bf16(a, b, c, 0, 0, 0);
}

// ---- proven agent-scope primitives (r2/r3) ---------------------------------
__device__ __forceinline__ void st_ag(unsigned* p, unsigned v) {
    __hip_atomic_store(p, v, __ATOMIC_RELAXED, __HIP_MEMORY_SCOPE_AGENT);
}
__device__ __forceinline__ unsigned ld_ag(const unsigned* p) {
    return __hip_atomic_load(p, __ATOMIC_RELAXED, __HIP_MEMORY_SCOPE_AGENT);
}
__device__ __forceinline__ void acq_ag() {
    __builtin_amdgcn_fence(__ATOMIC_ACQUIRE, "agent");
}

__device__ __forceinline__ void load_wfrag(const float* __restrict__ W,
                                           int col, int kk, s16x8& hi, s16x8& lo) {
    const float* p = W + (long)col * H + kk;
#pragma unroll
    for (int j = 0; j < 8; j++) {
        float w = p[j];
        unsigned short h = f2bf(w);
        float r = w - bf2f(h);
        hi[j] = (short)h;
        lo[j] = (short)f2bf(r);
    }
}

// six contiguous-k 16B A-fragments (plain cached loads; post-fence fresh)
__device__ __forceinline__ void ld6(const unsigned short* p, s16x8 (&d)[6]) {
#pragma unroll
    for (int ks = 0; ks < 6; ks++)
        d[ks] = *reinterpret_cast<const s16x8*>(p + ks * 32);
}

__device__ __forceinline__ unsigned wave_min(unsigned v) {
#pragma unroll
    for (int o = 32; o; o >>= 1) {
        unsigned u = (unsigned)__shfl_xor((int)v, o);
        v = v < u ? v : u;
    }
    return v;
}

// min over n flags (n<=24) >= T; then agent acquire + syncthreads.
__device__ __forceinline__ void waitn(const unsigned* f, int n, unsigned T, int tid) {
    if (tid < 64) {
        long spin = 0;
        for (;;) {
            unsigned v = 0xFFFFFFFFu;
            if (tid < n) v = ld_ag(f + tid);
            if (wave_min(v) >= T) break;
            __builtin_amdgcn_s_sleep(1);
            if (++spin > (1L << 20)) break;   // failsafe
        }
    }
    if (tid == 0) acq_ag();
    __syncthreads();
}

#define DRAIN() do { asm volatile("s_waitcnt vmcnt(0)" ::: "memory"); __syncthreads(); } while (0)

__global__ __launch_bounds__(256, 1) void rnn_persist(
    const float* __restrict__ x,
    const float* __restrict__ Wih1, const float* __restrict__ Whh1,
    const float* __restrict__ bih1, const float* __restrict__ bhh1,
    const float* __restrict__ Wih2, const float* __restrict__ Whh2,
    const float* __restrict__ bih2, const float* __restrict__ bhh2,
    const float* __restrict__ Wlin, const float* __restrict__ blin,
    float* __restrict__ out, unsigned char* __restrict__ ws)
{
    const int wg = blockIdx.x;
    const int tid = threadIdx.x;
    const int lane = tid & 63;
    const int w = tid >> 6;          // wave 0..3, K range [w*192, +192)
    const int l15 = lane & 15;
    const int lk8 = (lane >> 4) * 8;

    const int group = wg >> 5;       // 0..7 (16 batch rows each)
    const int lrank = wg & 31;       // 0..31 within group

    __shared__ float red[4][16][97];

    unsigned char* gb = ws + GRP_BASE + (size_t)group * GRP_STRIDE;
    unsigned* fL1 = (unsigned*)(gb + G_FL1);
    unsigned* fP1 = (unsigned*)(gb + G_FP1);
    unsigned* fH2 = (unsigned*)(gb + G_FH2);
    float* Pb = (float*)(gb + G_PB);
    unsigned short* h1hi[2] = {(unsigned short*)(gb + G_HB + 0 * HB_SZ), (unsigned short*)(gb + G_HB + 1 * HB_SZ)};
    unsigned short* h1lo[2] = {(unsigned short*)(gb + G_HB + 2 * HB_SZ), (unsigned short*)(gb + G_HB + 3 * HB_SZ)};
    unsigned short* h2hi[2] = {(unsigned short*)(gb + G_HB + 4 * HB_SZ), (unsigned short*)(gb + G_HB + 5 * HB_SZ)};
    unsigned short* h2lo[2] = {(unsigned short*)(gb + G_HB + 6 * HB_SZ), (unsigned short*)(gb + G_HB + 7 * HB_SZ)};

    const int kb0 = w * 192;

    if (lrank < NL1R) {
        // ------------------------- Layer-1 role ------------------------------
        const int c = lrank;
        const int col0 = c * 96;

        s16x8 whi[6][6], wlo[6][6];
#pragma unroll
        for (int ks = 0; ks < 6; ks++)
#pragma unroll
            for (int nt = 0; nt < 6; nt++)
                load_wfrag(Whh1, col0 + nt * 16 + l15, kb0 + ks * 32 + lk8,
                           whi[ks][nt], wlo[ks][nt]);

        // epilogue: one row (er), 6 consecutive cols per thread
        const int er = tid >> 4;
        const int ec0 = (tid & 15) * 6;
        const int b = group * GROWS + er;
        float bs[6], wi0[6], wi1[6];
#pragma unroll
        for (int j = 0; j < 6; j++) {
            int cg = col0 + ec0 + j;
            bs[j] = bih1[cg] + bhh1[cg];
            wi0[j] = Wih1[cg * 2 + 0];
            wi1[j] = Wih1[cg * 2 + 1];
        }
        // out-reduce constants (tid<128): value (orow, ooo), 32 lanes each
        const int ov = tid >> 5;
        const int oj = tid & 31;
        const int orow = 2 * c + (ov >> 1);
        const int ooo = ov & 1;
        const float blv = blin[ooo];

        for (int t = 0; t < T_LEN; t++) {
            const int cur = t & 1, nxt = cur ^ 1;
            float x0 = x[b * 2048 + t];
            float x1 = x[b * 2048 + 1024 + t];

            if (t) waitn(fL1, 8, (unsigned)t, tid);   // h1(t-1) ready + fence

            s16x8 ah[6], al[6];
            ld6(h1hi[cur] + l15 * H + kb0 + lk8, ah);
            ld6(h1lo[cur] + l15 * H + kb0 + lk8, al);

            fx4 acc[6];
#pragma unroll
            for (int nt = 0; nt < 6; nt++) acc[nt] = fx4{0.f, 0.f, 0.f, 0.f};
#pragma unroll
            for (int ks = 0; ks < 6; ks++)
#pragma unroll
                for (int nt = 0; nt < 6; nt++) {
                    acc[nt] = mfma16(ah[ks], whi[ks][nt], acc[nt]);
                    acc[nt] = mfma16(ah[ks], wlo[ks][nt], acc[nt]);
                    acc[nt] = mfma16(al[ks], whi[ks][nt], acc[nt]);
                }

#pragma unroll
            for (int nt = 0; nt < 6; nt++)
#pragma unroll
                for (int i = 0; i < 4; i++)
                    red[w][(lane >> 4) * 4 + i][nt * 16 + l15] = acc[nt][i];
            __syncthreads();

            unsigned hw[3], lw[3];
#pragma unroll
            for (int jj = 0; jj < 3; jj++) {
                unsigned hp = 0, lp = 0;
#pragma unroll
                for (int k = 0; k < 2; k++) {
                    int j = jj * 2 + k;
                    int cc = ec0 + j;
                    float v = red[0][er][cc] + red[1][er][cc] + red[2][er][cc] + red[3][er][cc];
                    v += x0 * wi0[j] + x1 * wi1[j] + bs[j];
                    v = tanhf(v);
                    unsigned short hb = f2bf(v);
                    unsigned short lb = f2bf(v - bf2f(hb));
                    hp |= ((unsigned)hb) << (16 * k);
                    lp |= ((unsigned)lb) << (16 * k);
                }
                hw[jj] = hp; lw[jj] = lp;
            }

            // anti-dep + P(t-2) gate
            if (t) waitn(fP1, 24, (unsigned)t, tid);

            // out(t-2) reduce BEFORE our arrival flag (closes P-slot race)
            if (t >= 2 && tid < 128) {
                float p = 0.f;
                if (oj < 24)
                    p = Pb[(((t & 1) * 16 + orow) * 2 + ooo) * 24 + oj];
#pragma unroll
                for (int o = 16; o; o >>= 1) p += __shfl_down(p, o, 32);
                if (oj == 0) out[(group * GROWS + orow) * 2048 + ooo * 1024 + (t - 2)] = p + blv;
            }

            unsigned* Dh = (unsigned*)(h1hi[nxt] + (long)er * H + col0 + ec0);
            unsigned* Dl = (unsigned*)(h1lo[nxt] + (long)er * H + col0 + ec0);
            st_ag(Dh + 0, hw[0]); st_ag(Dh + 1, hw[1]); st_ag(Dh + 2, hw[2]);
            st_ag(Dl + 0, lw[0]); st_ag(Dl + 1, lw[1]); st_ag(Dl + 2, lw[2]);

            DRAIN();
            if (tid == 0) st_ag(fL1 + c, (unsigned)(t + 1));
        }

        // final: fH2>=T covers P(T-2) and P(T-1)
        if (tid < 64) {
            long spin = 0;
            for (;;) {
                unsigned v = 0xFFFFFFFFu;
                if (tid < 24) v = ld_ag(fH2 + tid);
                if (wave_min(v) >= (unsigned)T_LEN) break;
                __builtin_amdgcn_s_sleep(1);
                if (++spin > (1L << 20)) break;
            }
        }
        if (tid == 0) acq_ag();
        __syncthreads();
        if (tid < 128) {
#pragma unroll
            for (int par = 0; par < 2; par++) {   // par0 -> T-2, par1 -> T-1
                float p = 0.f;
                if (oj < 24)
                    p = Pb[((par * 16 + orow) * 2 + ooo) * 24 + oj];
#pragma unroll
                for (int o = 16; o; o >>= 1) p += __shfl_down(p, o, 32);
                if (oj == 0) out[(group * GROWS + orow) * 2048 + ooo * 1024 + (T_LEN - 2 + par)] = p + blv;
            }
        }
    } else {
        // ------------------------- Layer-2 role ------------------------------
        const int c = lrank - NL1R;      // 0..23
        const int col0 = c * 32;

        s16x8 ghi[2][6], glo[2][6], ihi[2][6], ilo[2][6];
#pragma unroll
        for (int nt = 0; nt < 2; nt++)
#pragma unroll
            for (int ks = 0; ks < 6; ks++) {
                load_wfrag(Whh2, col0 + nt * 16 + l15, kb0 + ks * 32 + lk8, ghi[nt][ks], glo[nt][ks]);
                load_wfrag(Wih2, col0 + nt * 16 + l15, kb0 + ks * 32 + lk8, ihi[nt][ks], ilo[nt][ks]);
            }

        const int er = tid >> 4;             // 0..15
        const int ec0 = (tid & 15) * 2;      // 0..30
        const float bsA = bih2[col0 + ec0] + bhh2[col0 + ec0];
        const float bsB = bih2[col0 + ec0 + 1] + bhh2[col0 + ec0 + 1];

        const int ro = tid >> 1, oo = tid & 1;   // tid<32: P-partial dot
        float wl[32];
        if (tid < 32) {
#pragma unroll
            for (int cc = 0; cc < 32; cc++) wl[cc] = Wlin[oo * H + col0 + cc];
        }

        for (int t = 0; t < T_LEN; t++) {
            const int rb = (t + 1) & 1;     // h2(t-1) buffer
            const int wb = t & 1;           // h2(t) buffer
            const int nxt = (t & 1) ^ 1;    // h1(t) buffer

            if (t) waitn(fH2, 24, (unsigned)t, tid);   // h2(t-1) ready + fence

            s16x8 ah[6], al[6];
            ld6(h2hi[rb] + l15 * H + kb0 + lk8, ah);
            ld6(h2lo[rb] + l15 * H + kb0 + lk8, al);

            fx4 a2[2];
            a2[0] = fx4{0.f, 0.f, 0.f, 0.f};
            a2[1] = fx4{0.f, 0.f, 0.f, 0.f};
#pragma unroll
            for (int ks = 0; ks < 6; ks++)
#pragma unroll
                for (int nt = 0; nt < 2; nt++) {
                    a2[nt] = mfma16(ah[ks], ghi[nt][ks], a2[nt]);
                    a2[nt] = mfma16(ah[ks], glo[nt][ks], a2[nt]);
                    a2[nt] = mfma16(al[ks], ghi[nt][ks], a2[nt]);
                }

            DRAIN();   // phase1 reads consumed
            if (tid == 0) st_ag(fP1 + c, (unsigned)(t + 1));

            waitn(fL1, 8, (unsigned)(t + 1), tid);     // h1(t) ready + fence

            ld6(h1hi[nxt] + l15 * H + kb0 + lk8, ah);
            ld6(h1lo[nxt] + l15 * H + kb0 + lk8, al);
#pragma unroll
            for (int ks = 0; ks < 6; ks++)
#pragma unroll
                for (int nt = 0; nt < 2; nt++) {
                    a2[nt] = mfma16(ah[ks], ihi[nt][ks], a2[nt]);
                    a2[nt] = mfma16(ah[ks], ilo[nt][ks], a2[nt]);
                    a2[nt] = mfma16(al[ks], ihi[nt][ks], a2[nt]);
                }

#pragma unroll
            for (int nt = 0; nt < 2; nt++)
#pragma unroll
                for (int i = 0; i < 4; i++)
                    red[w][(lane >> 4) * 4 + i][nt * 16 + l15] = a2[nt][i];
            __syncthreads();

            float v0 = red[0][er][ec0] + red[1][er][ec0] + red[2][er][ec0] + red[3][er][ec0] + bsA;
            float v1 = red[0][er][ec0 + 1] + red[1][er][ec0 + 1] + red[2][er][ec0 + 1] + red[3][er][ec0 + 1] + bsB;
            v0 = tanhf(v0); v1 = tanhf(v1);
            unsigned short hb0 = f2bf(v0), hb1 = f2bf(v1);
            unsigned hp = ((unsigned)hb0) | (((unsigned)hb1) << 16);
            unsigned lp = ((unsigned)f2bf(v0 - bf2f(hb0))) | (((unsigned)f2bf(v1 - bf2f(hb1))) << 16);
            st_ag((unsigned*)(h2hi[wb] + (long)er * H + col0 + ec0), hp);
            st_ag((unsigned*)(h2lo[wb] + (long)er * H + col0 + ec0), lp);
            red[0][er][ec0] = v0;
            red[0][er][ec0 + 1] = v1;
            __syncthreads();

            if (tid < 32) {
                float s = 0.f;
#pragma unroll
                for (int cc = 0; cc < 32; cc++) s += red[0][ro][cc] * wl[cc];
                st_ag((unsigned*)&Pb[((wb * 16 + ro) * 2 + oo) * 24 + c], __float_as_uint(s));
            }

            DRAIN();
            if (tid == 0) st_ag(fH2 + c, (unsigned)(t + 1));
        }
    }
}

extern "C" void kernel_launch(void* const* d_in, const int* in_sizes, int n_in,
                              void* d_out, int out_size, void* d_ws, size_t ws_size,
                              hipStream_t stream) {
    const float* x    = (const float*)d_in[0];
    const float* Wih1 = (const float*)d_in[1];
    const float* Whh1 = (const float*)d_in[2];
    const float* bih1 = (const float*)d_in[3];
    const float* bhh1 = (const float*)d_in[4];
    const float* Wih2 = (const float*)d_in[5];
    const float* Whh2 = (const float*)d_in[6];
    const float* bih2 = (const float*)d_in[7];
    const float* bhh2 = (const float*)d_in[8];
    const float* Wlin = (const float*)d_in[9];
    const float* blin = (const float*)d_in[10];

    // Zero flags + h-state (initial h = 0).  P fully written before read;
    // out fully overwritten by owned stores.
    hipMemsetAsync(d_ws, 0, WS_TOTAL, stream);

    rnn_persist<<<NWG, 256, 0, stream>>>(x, Wih1, Whh1, bih1, bhh1,
                                         Wih2, Whh2, bih2, bhh2,
                                         Wlin, blin, (float*)d_out,
                                         (unsigned char*)d_ws);
}